// Round 4
// baseline (546.288 us; speedup 1.0000x reference)
//
#include <hip/hip_runtime.h>
#include <hip/hip_bf16.h>

#define NN 32768
#define NE 524288
#define HID 128

typedef unsigned short u16;
typedef unsigned int u32;
typedef __bf16 bf16x8 __attribute__((ext_vector_type(8)));
typedef float f32x4 __attribute__((ext_vector_type(4)));

__device__ __forceinline__ u16 f2bf(float f) {
  return __builtin_bit_cast(u16, (__bf16)f);   // RNE via v_cvt
}
__device__ __forceinline__ float silu_f(float v) {
  return v * __builtin_amdgcn_rcpf(1.f + __expf(-v));
}
__device__ __forceinline__ bf16x8 cvt8(float4 a, float4 b) {
  bf16x8 r;
  r[0] = (__bf16)a.x; r[1] = (__bf16)a.y; r[2] = (__bf16)a.z; r[3] = (__bf16)a.w;
  r[4] = (__bf16)b.x; r[5] = (__bf16)b.y; r[6] = (__bf16)b.z; r[7] = (__bf16)b.w;
  return r;
}

// async global->LDS, 16B per lane. LDS dest: wave-uniform base + lane*16.
__device__ __forceinline__ void gld16(const void* g, void* l) {
  __builtin_amdgcn_global_load_lds(
      (const __attribute__((address_space(1))) u32*)g,
      (__attribute__((address_space(3))) u32*)l, 16, 0, 0);
}

// ---------------------------------------------------------------- prep ----
// x -> bf16, weights -> bf16 col-major wT[col][k]; fused recv-degree count
// (cnt zeroed by hipMemsetAsync before this kernel).
__global__ __launch_bounds__(256) void prep_k(
    const float* __restrict__ x, const float* __restrict__ w1,
    const float* __restrict__ w2, const float* __restrict__ wu1,
    const float* __restrict__ wu2, const int* __restrict__ recv,
    u16* __restrict__ xb, u16* __restrict__ w1T, u16* __restrict__ w2T,
    u16* __restrict__ wu1T, u16* __restrict__ wu2T, int* __restrict__ cnt)
{
  int i = blockIdx.x * 256 + threadIdx.x;   // grid covers exactly NN*HID
  xb[i] = f2bf(x[i]);
  if (i < NE) atomicAdd(&cnt[recv[i]], 1);
  if (i < 3 * 128 * 128) {                  // w1T [s][c][k]
    int k = i & 127, c = (i >> 7) & 127, s = i >> 14;
    w1T[i] = f2bf(w1[(s * 128 + k) * 128 + c]);
  }
  if (i < 128 * 128) { int k = i & 127, c = i >> 7; w2T[i]  = f2bf(w2[k * 128 + c]); }
  if (i < 256 * 128) { int k = i & 127, c = i >> 7; wu1T[i] = f2bf(wu1[k * 256 + c]); }
  if (i < 128 * 256) { int k = i & 255, c = i >> 8; wu2T[i] = f2bf(wu2[k * 128 + c]); }
}

// exclusive scan of cnt[NN] -> off[NN+1]; cursor = copy of off
__global__ __launch_bounds__(1024) void scan_k(const int* __restrict__ cnt,
                                               int* __restrict__ off,
                                               int* __restrict__ cursor)
{
  __shared__ int part[1024];
  const int tid = threadIdx.x;
  const int base = tid * 32;
  int v[32];
  int s = 0;
  #pragma unroll
  for (int j = 0; j < 32; ++j) { v[j] = cnt[base + j]; s += v[j]; }
  part[tid] = s;
  __syncthreads();
  #pragma unroll 1
  for (int d = 1; d < 1024; d <<= 1) {
    int t = (tid >= d) ? part[tid - d] : 0;
    __syncthreads();
    part[tid] += t;
    __syncthreads();
  }
  int ex = part[tid] - s;
  #pragma unroll
  for (int j = 0; j < 32; ++j) {
    off[base + j] = ex;
    cursor[base + j] = ex;
    ex += v[j];
  }
  if (tid == 1023) off[NN] = ex;
}

__global__ __launch_bounds__(256) void scatter_k(const int* __restrict__ recv,
                                                 int* __restrict__ cursor,
                                                 int* __restrict__ eperm)
{
  int e = blockIdx.x * 256 + threadIdx.x;
  int r = recv[e];
  int pos = atomicAdd(&cursor[r], 1);
  eperm[pos] = e;
}

// ------------------------------------------------------------ edge MLP ----
// 128 edges/block, 8 waves, wave tile 64 rows x 32 cols (wr=w>>2, wc=w&3).
// A slices s0 (x[send]) / s1 (x[recv]) staged once via global_load_lds into
// 2x32KB swizzled LDS buffers; eattr slice goes DIRECT global->reg->cvt_pk.
// B fragments direct from L2-resident col-major w1T/w2T. 3 barriers total.
__global__ __launch_bounds__(512, 4) void edge_mlp(
    const u16* __restrict__ xb, const float* __restrict__ eattr,
    const int* __restrict__ send, const int* __restrict__ recv,
    const u16* __restrict__ w1T, const float* __restrict__ b1,
    const u16* __restrict__ w2T, const float* __restrict__ b2,
    float* __restrict__ msg_out)
{
  __shared__ u16 sA[2][128 * 128];   // [slice][row*128 + swz-chunk layout]

  const int tid  = threadIdx.x;
  const int lane = tid & 63;
  const int w    = tid >> 6;
  const int wr   = w >> 2;              // 0..1: 64-row stripe
  const int wc   = w & 3;               // 0..3: 32-col quarter
  const int fr   = lane & 15;
  const int fkq  = lane >> 4;           // k-quarter within fragment
  const int orow = fkq * 4;
  const int e0   = blockIdx.x * 128;

  const int lrow4 = lane >> 4;          // row within 4-row staging group
  const int schk  = lane & 15;          // linear LDS chunk this lane fills

  // per-lane bias values for this wave's 2 col-fragments
  float b1v[2] = { b1[wc * 32 + fr], b1[wc * 32 + 16 + fr] };
  float b2v[2] = { b2[wc * 32 + fr], b2[wc * 32 + 16 + fr] };

  // stage s0 (x[send]) -> sA[0], s1 (x[recv]) -> sA[1]
  #pragma unroll
  for (int i = 0; i < 4; ++i) {
    int rloc = w * 16 + i * 4 + lrow4;
    int gchk = (schk ^ (rloc & 7)) << 3;
    int ns = send[e0 + rloc], nr = recv[e0 + rloc];
    gld16(xb + ((size_t)ns << 7) + gchk, &sA[0][(w * 16 + i * 4) << 7]);
    gld16(xb + ((size_t)nr << 7) + gchk, &sA[1][(w * 16 + i * 4) << 7]);
  }

  f32x4 acc[4][2];
  #pragma unroll
  for (int m = 0; m < 4; ++m)
    #pragma unroll
    for (int n = 0; n < 2; ++n)
      #pragma unroll
      for (int r = 0; r < 4; ++r) acc[m][n][r] = 0.f;

  __syncthreads();   // glds drained (compiler vmcnt0) -> both A-slices ready

  // ---- layer 1, slices 0 and 1 (A from LDS, B from global L2) ----
  #pragma unroll
  for (int s = 0; s < 2; ++s) {
    const u16* buf = sA[s];
    const u16* wp  = w1T + ((size_t)s << 14) + ((wc * 32 + fr) << 7) + fkq * 8;
    #pragma unroll
    for (int kk = 0; kk < 4; ++kk) {
      bf16x8 bF[2], aF[4];
      #pragma unroll
      for (int n = 0; n < 2; ++n)
        bF[n] = __builtin_bit_cast(bf16x8,
            *reinterpret_cast<const uint4*>(wp + n * 2048 + kk * 32));
      #pragma unroll
      for (int m = 0; m < 4; ++m) {
        int row = wr * 64 + m * 16 + fr;
        int ch = (kk * 4 + fkq) ^ (row & 7);
        aF[m] = __builtin_bit_cast(bf16x8,
            *reinterpret_cast<const uint4*>(buf + (row << 7) + (ch << 3)));
      }
      __builtin_amdgcn_s_setprio(1);
      #pragma unroll
      for (int m = 0; m < 4; ++m)
        #pragma unroll
        for (int n = 0; n < 2; ++n)
          acc[m][n] = __builtin_amdgcn_mfma_f32_16x16x32_bf16(aF[m], bF[n], acc[m][n], 0, 0, 0);
      __builtin_amdgcn_s_setprio(0);
    }
  }

  // ---- layer 1, slice 2: eattr direct global->reg->bf16 ----
  {
    const u16* wp = w1T + (2 << 14) + ((wc * 32 + fr) << 7) + fkq * 8;
    #pragma unroll
    for (int m = 0; m < 4; ++m) {
      const float* ep = eattr + ((size_t)(e0 + wr * 64 + m * 16 + fr) << 7) + fkq * 8;
      float4 r0[4], r1[4];
      #pragma unroll
      for (int kk = 0; kk < 4; ++kk) {
        r0[kk] = *reinterpret_cast<const float4*>(ep + kk * 32);
        r1[kk] = *reinterpret_cast<const float4*>(ep + kk * 32 + 4);
      }
      #pragma unroll
      for (int kk = 0; kk < 4; ++kk) {
        bf16x8 aF = cvt8(r0[kk], r1[kk]);
        bf16x8 bF[2];
        #pragma unroll
        for (int n = 0; n < 2; ++n)
          bF[n] = __builtin_bit_cast(bf16x8,
              *reinterpret_cast<const uint4*>(wp + n * 2048 + kk * 32));
        __builtin_amdgcn_s_setprio(1);
        #pragma unroll
        for (int n = 0; n < 2; ++n)
          acc[m][n] = __builtin_amdgcn_mfma_f32_16x16x32_bf16(aF, bF[n], acc[m][n], 0, 0, 0);
        __builtin_amdgcn_s_setprio(0);
      }
    }
  }

  __syncthreads();   // everyone done reading sA[0]

  // hidden = silu(acc + b1) -> sA[0] (swizzled b16 writes); reset acc
  #pragma unroll
  for (int m = 0; m < 4; ++m) {
    #pragma unroll
    for (int n = 0; n < 2; ++n) {
      int c = wc * 32 + n * 16 + fr;
      #pragma unroll
      for (int r = 0; r < 4; ++r) {
        int row = wr * 64 + m * 16 + orow + r;
        sA[0][(row << 7) + (((c >> 3) ^ (row & 7)) << 3) + (c & 7)] =
            f2bf(silu_f(acc[m][n][r] + b1v[n]));
        acc[m][n][r] = 0.f;
      }
    }
  }
  __syncthreads();

  // ---- layer 2 (K=128): A = hidden from sA[0], B = w2T from L2 ----
  {
    const u16* wp = w2T + ((wc * 32 + fr) << 7) + fkq * 8;
    #pragma unroll
    for (int kk = 0; kk < 4; ++kk) {
      bf16x8 bF[2], aF[4];
      #pragma unroll
      for (int n = 0; n < 2; ++n)
        bF[n] = __builtin_bit_cast(bf16x8,
            *reinterpret_cast<const uint4*>(wp + n * 2048 + kk * 32));
      #pragma unroll
      for (int m = 0; m < 4; ++m) {
        int row = wr * 64 + m * 16 + fr;
        int ch = (kk * 4 + fkq) ^ (row & 7);
        aF[m] = __builtin_bit_cast(bf16x8,
            *reinterpret_cast<const uint4*>(sA[0] + (row << 7) + (ch << 3)));
      }
      __builtin_amdgcn_s_setprio(1);
      #pragma unroll
      for (int m = 0; m < 4; ++m)
        #pragma unroll
        for (int n = 0; n < 2; ++n)
          acc[m][n] = __builtin_amdgcn_mfma_f32_16x16x32_bf16(aF[m], bF[n], acc[m][n], 0, 0, 0);
      __builtin_amdgcn_s_setprio(0);
    }
  }

  // epilogue: msg = silu(acc + b2)
  #pragma unroll
  for (int m = 0; m < 4; ++m) {
    float* mp = msg_out + ((size_t)(e0 + wr * 64 + m * 16 + orow) << 7) + wc * 32 + fr;
    #pragma unroll
    for (int r = 0; r < 4; ++r)
      #pragma unroll
      for (int n = 0; n < 2; ++n)
        mp[r * 128 + n * 16] = silu_f(acc[m][n][r] + b2v[n]);
  }
}

// -------------------------------------------------------- aggregation ----
// one wave per node: gather msg rows via CSR, mean, + x -> xin (f32), xob (bf16)
__global__ __launch_bounds__(256) void agg_k(
    const float* __restrict__ msg, const int* __restrict__ off,
    const int* __restrict__ eperm, const float* __restrict__ x,
    float* __restrict__ xin, u16* __restrict__ xob)
{
  const int wid = threadIdx.x >> 6, lane = threadIdx.x & 63;
  const int n = blockIdx.x * 4 + wid;
  const int j0 = off[n], j1 = off[n + 1];
  float ax = 0.f, ay = 0.f;
  int j = j0;
  for (; j + 3 < j1; j += 4) {
    int ea = eperm[j], eb = eperm[j + 1], ec = eperm[j + 2], ed = eperm[j + 3];
    float2 va = reinterpret_cast<const float2*>(msg + (size_t)ea * HID)[lane];
    float2 vb = reinterpret_cast<const float2*>(msg + (size_t)eb * HID)[lane];
    float2 vc = reinterpret_cast<const float2*>(msg + (size_t)ec * HID)[lane];
    float2 vd = reinterpret_cast<const float2*>(msg + (size_t)ed * HID)[lane];
    ax += (va.x + vb.x) + (vc.x + vd.x);
    ay += (va.y + vb.y) + (vc.y + vd.y);
  }
  for (; j < j1; ++j) {
    int ea = eperm[j];
    float2 va = reinterpret_cast<const float2*>(msg + (size_t)ea * HID)[lane];
    ax += va.x; ay += va.y;
  }
  float inv = (j1 > j0) ? 1.f / (float)(j1 - j0) : 1.f;
  float2 xv = reinterpret_cast<const float2*>(x + (size_t)n * HID)[lane];
  float x0 = xv.x + ax * inv, x1 = xv.y + ay * inv;
  reinterpret_cast<float2*>(xin + (size_t)n * HID)[lane] = make_float2(x0, x1);
  reinterpret_cast<unsigned*>(xob)[n * 64 + lane] =
      (unsigned)f2bf(x0) | ((unsigned)f2bf(x1) << 16);
}

// ----------------------------------------------------------- update MLP ----
// t = silu(xin @ wu1 + bu1)  [NN,256] — no LDS, B direct from L2
__global__ __launch_bounds__(256, 4) void mlp1_k(
    const u16* __restrict__ xob, const u16* __restrict__ wu1T,
    const float* __restrict__ bu1, u16* __restrict__ t)
{
  const int tid = threadIdx.x, lane = tid & 63, wid = tid >> 6;
  const int wr = wid >> 1, wc = wid & 1;
  const int fr = lane & 15, fkq = lane >> 4, orow = fkq * 4;
  const int n0 = blockIdx.x * 64;

  f32x4 acc[2][8];
  #pragma unroll
  for (int m = 0; m < 2; ++m)
    #pragma unroll
    for (int n = 0; n < 8; ++n)
      #pragma unroll
      for (int r = 0; r < 4; ++r) acc[m][n][r] = 0.f;

  const u16* wp = wu1T + ((wc * 128 + fr) << 7) + fkq * 8;
  #pragma unroll
  for (int kk = 0; kk < 4; ++kk) {
    bf16x8 aF[2], bF[8];
    #pragma unroll
    for (int m = 0; m < 2; ++m)
      aF[m] = __builtin_bit_cast(bf16x8, *reinterpret_cast<const uint4*>(
          xob + ((size_t)(n0 + wr * 32 + m * 16 + fr) << 7) + kk * 32 + fkq * 8));
    #pragma unroll
    for (int n = 0; n < 8; ++n)
      bF[n] = __builtin_bit_cast(bf16x8,
          *reinterpret_cast<const uint4*>(wp + n * 2048 + kk * 32));
    __builtin_amdgcn_s_setprio(1);
    #pragma unroll
    for (int m = 0; m < 2; ++m)
      #pragma unroll
      for (int n = 0; n < 8; ++n)
        acc[m][n] = __builtin_amdgcn_mfma_f32_16x16x32_bf16(aF[m], bF[n], acc[m][n], 0, 0, 0);
    __builtin_amdgcn_s_setprio(0);
  }
  #pragma unroll
  for (int n = 0; n < 8; ++n) {
    int col = wc * 128 + n * 16 + fr;
    float bb = bu1[col];
    #pragma unroll
    for (int m = 0; m < 2; ++m) {
      int row = n0 + wr * 32 + m * 16 + orow;
      #pragma unroll
      for (int r = 0; r < 4; ++r)
        t[(size_t)(row + r) * 256 + col] = f2bf(silu_f(acc[m][n][r] + bb));
    }
  }
}

// xo = xin + t @ wu2 + bu2 — no LDS, B direct from L2
__global__ __launch_bounds__(256, 4) void mlp2_k(
    const u16* __restrict__ t, const u16* __restrict__ wu2T,
    const float* __restrict__ bu2, const float* __restrict__ xin,
    float* __restrict__ xo)
{
  const int tid = threadIdx.x, lane = tid & 63, wid = tid >> 6;
  const int wr = wid >> 1, wc = wid & 1;
  const int fr = lane & 15, fkq = lane >> 4, orow = fkq * 4;
  const int n0 = blockIdx.x * 64;

  f32x4 acc[2][4];
  #pragma unroll
  for (int m = 0; m < 2; ++m)
    #pragma unroll
    for (int n = 0; n < 4; ++n)
      #pragma unroll
      for (int r = 0; r < 4; ++r) acc[m][n][r] = 0.f;

  const u16* wp = wu2T + (size_t)(wc * 64 + fr) * 256 + fkq * 8;
  #pragma unroll
  for (int kk = 0; kk < 8; ++kk) {
    bf16x8 aF[2], bF[4];
    #pragma unroll
    for (int m = 0; m < 2; ++m)
      aF[m] = __builtin_bit_cast(bf16x8, *reinterpret_cast<const uint4*>(
          t + (size_t)(n0 + wr * 32 + m * 16 + fr) * 256 + kk * 32 + fkq * 8));
    #pragma unroll
    for (int n = 0; n < 4; ++n)
      bF[n] = __builtin_bit_cast(bf16x8,
          *reinterpret_cast<const uint4*>(wp + n * 4096 + kk * 32));
    __builtin_amdgcn_s_setprio(1);
    #pragma unroll
    for (int m = 0; m < 2; ++m)
      #pragma unroll
      for (int n = 0; n < 4; ++n)
        acc[m][n] = __builtin_amdgcn_mfma_f32_16x16x32_bf16(aF[m], bF[n], acc[m][n], 0, 0, 0);
    __builtin_amdgcn_s_setprio(0);
  }
  #pragma unroll
  for (int m = 0; m < 2; ++m) {
    #pragma unroll
    for (int r = 0; r < 4; ++r) {
      int gn = n0 + wr * 32 + m * 16 + orow + r;
      #pragma unroll
      for (int n = 0; n < 4; ++n) {
        int col = wc * 64 + n * 16 + fr;
        xo[(size_t)gn * HID + col] =
            xin[(size_t)gn * HID + col] + acc[m][n][r] + bu2[col];
      }
    }
  }
}

// -------------------------------------------------------------- launch ----
extern "C" void kernel_launch(void* const* d_in, const int* in_sizes, int n_in,
                              void* d_out, int out_size, void* d_ws, size_t ws_size,
                              hipStream_t stream)
{
  (void)in_sizes; (void)n_in; (void)out_size; (void)ws_size;
  const float* x     = (const float*)d_in[0];
  const float* eattr = (const float*)d_in[1];
  const int*   edges = (const int*)d_in[2];
  const float* w1  = (const float*)d_in[3];
  const float* b1  = (const float*)d_in[4];
  const float* w2  = (const float*)d_in[5];
  const float* b2  = (const float*)d_in[6];
  const float* wu1 = (const float*)d_in[7];
  const float* bu1 = (const float*)d_in[8];
  const float* wu2 = (const float*)d_in[9];
  const float* bu2 = (const float*)d_in[10];

  float* xo  = (float*)d_out;
  float* msg = xo + (size_t)NN * HID;

  char* p = (char*)d_ws;
  u16* xb    = (u16*)p; p += (size_t)NN * HID * 2;
  u16* w1T   = (u16*)p; p += 384 * 128 * 2;
  u16* w2T   = (u16*)p; p += 128 * 128 * 2;
  u16* wu1T  = (u16*)p; p += 256 * 128 * 2;
  u16* wu2T  = (u16*)p; p += 128 * 256 * 2;
  u16* xob   = (u16*)p; p += (size_t)NN * HID * 2;
  u16* tbuf  = (u16*)p; p += (size_t)NN * 256 * 2;
  float* xin = (float*)p; p += (size_t)NN * HID * 4;
  int* cnt    = (int*)p; p += (size_t)NN * 4;
  int* off    = (int*)p; p += (size_t)(NN + 64) * 4;
  int* cursor = (int*)p; p += (size_t)NN * 4;
  int* eperm  = (int*)p; p += (size_t)NE * 4;

  const int* send = edges;
  const int* recv = edges + NE;

  hipMemsetAsync(cnt, 0, (size_t)NN * 4, stream);
  prep_k<<<NN * HID / 256, 256, 0, stream>>>(x, w1, w2, wu1, wu2, recv,
                                             xb, w1T, w2T, wu1T, wu2T, cnt);
  scan_k<<<1, 1024, 0, stream>>>(cnt, off, cursor);
  scatter_k<<<NE / 256, 256, 0, stream>>>(recv, cursor, eperm);
  edge_mlp<<<NE / 128, 512, 0, stream>>>(xb, eattr, send, recv,
                                         w1T, b1, w2T, b2, msg);
  agg_k<<<NN / 4, 256, 0, stream>>>(msg, off, eperm, x, xin, xob);
  mlp1_k<<<NN / 64, 256, 0, stream>>>(xob, wu1T, bu1, tbuf);
  mlp2_k<<<NN / 64, 256, 0, stream>>>(tbuf, wu2T, bu2, xin, xo);
}

// Round 5
// 390.939 us; speedup vs baseline: 1.3974x; 1.3974x over previous
//
#include <hip/hip_runtime.h>
#include <hip/hip_bf16.h>

#define NN 32768
#define NE 524288
#define HID 128

typedef unsigned short u16;
typedef unsigned int u32;
typedef __bf16 bf16x8 __attribute__((ext_vector_type(8)));
typedef float f32x4 __attribute__((ext_vector_type(4)));

__device__ __forceinline__ u16 f2bf(float f) {
  return __builtin_bit_cast(u16, (__bf16)f);   // RNE via v_cvt
}
__device__ __forceinline__ float silu_f(float v) {
  return v * __builtin_amdgcn_rcpf(1.f + __expf(-v));
}
__device__ __forceinline__ bf16x8 cvt8(float4 a, float4 b) {
  bf16x8 r;
  r[0] = (__bf16)a.x; r[1] = (__bf16)a.y; r[2] = (__bf16)a.z; r[3] = (__bf16)a.w;
  r[4] = (__bf16)b.x; r[5] = (__bf16)b.y; r[6] = (__bf16)b.z; r[7] = (__bf16)b.w;
  return r;
}

// async global->LDS, 16B/lane; LDS dest = wave-uniform base + lane*16
__device__ __forceinline__ void gld16(const void* g, void* l) {
  __builtin_amdgcn_global_load_lds(
      (const __attribute__((address_space(1))) u32*)g,
      (__attribute__((address_space(3))) u32*)l, 16, 0, 0);
}

// counted waits + raw barrier (m201 pattern). sched_barrier pins motion.
#define WV(N)  do { asm volatile("s_waitcnt vmcnt(" #N ")" ::: "memory"); \
                    __builtin_amdgcn_sched_barrier(0); } while (0)
#define WVL(N) do { asm volatile("s_waitcnt vmcnt(" #N ") lgkmcnt(0)" ::: "memory"); \
                    __builtin_amdgcn_sched_barrier(0); } while (0)
#define WL()   do { asm volatile("s_waitcnt lgkmcnt(0)" ::: "memory"); \
                    __builtin_amdgcn_sched_barrier(0); } while (0)
__device__ __forceinline__ void bar() {
  __builtin_amdgcn_sched_barrier(0);
  __builtin_amdgcn_s_barrier();
  __builtin_amdgcn_sched_barrier(0);
}

// ---------------------------------------------------------------- prep ----
// x->bf16; w1/w2 -> col-major + 16B-chunk XOR pre-swizzle (glds lands swizzled);
// wu1/wu2 -> plain col-major; fused recv-degree count (cnt pre-zeroed).
__global__ __launch_bounds__(256) void prep_k(
    const float* __restrict__ x, const float* __restrict__ w1,
    const float* __restrict__ w2, const float* __restrict__ wu1,
    const float* __restrict__ wu2, const int* __restrict__ recv,
    u16* __restrict__ xb, u16* __restrict__ w1Ts, u16* __restrict__ w2Ts,
    u16* __restrict__ wu1T, u16* __restrict__ wu2T, int* __restrict__ cnt)
{
  int i = blockIdx.x * 256 + threadIdx.x;   // grid covers exactly NN*HID
  xb[i] = f2bf(x[i]);
  if (i < NE) atomicAdd(&cnt[recv[i]], 1);
  if (i < 3 * 128 * 128) {                  // w1Ts [s][c][q^(c&7)][j]
    int j = i & 7, qs = (i >> 3) & 15, c = (i >> 7) & 127, s = i >> 14;
    int k = s * 128 + ((qs ^ (c & 7)) << 3) + j;
    w1Ts[i] = f2bf(w1[k * 128 + c]);
  }
  if (i < 128 * 128) {                      // w2Ts [c][q^(c&7)][j]
    int j = i & 7, qs = (i >> 3) & 15, c = i >> 7;
    int k = ((qs ^ (c & 7)) << 3) + j;
    w2Ts[i] = f2bf(w2[k * 128 + c]);
  }
  if (i < 256 * 128) { int c = i >> 7, k = i & 127; wu1T[i] = f2bf(wu1[k * 256 + c]); }
  if (i < 128 * 256) { int c = i >> 8, k = i & 255; wu2T[i] = f2bf(wu2[k * 128 + c]); }
}

// exclusive scan of cnt[NN] -> off[NN+1]; cursor = copy of off
__global__ __launch_bounds__(1024) void scan_k(const int* __restrict__ cnt,
                                               int* __restrict__ off,
                                               int* __restrict__ cursor)
{
  __shared__ int part[1024];
  const int tid = threadIdx.x;
  const int base = tid * 32;
  int v[32];
  int s = 0;
  #pragma unroll
  for (int j = 0; j < 32; ++j) { v[j] = cnt[base + j]; s += v[j]; }
  part[tid] = s;
  __syncthreads();
  #pragma unroll 1
  for (int d = 1; d < 1024; d <<= 1) {
    int t = (tid >= d) ? part[tid - d] : 0;
    __syncthreads();
    part[tid] += t;
    __syncthreads();
  }
  int ex = part[tid] - s;
  #pragma unroll
  for (int j = 0; j < 32; ++j) {
    off[base + j] = ex;
    cursor[base + j] = ex;
    ex += v[j];
  }
  if (tid == 1023) off[NN] = ex;
}

__global__ __launch_bounds__(256) void scatter_k(const int* __restrict__ recv,
                                                 int* __restrict__ cursor,
                                                 int* __restrict__ eperm)
{
  int e = blockIdx.x * 256 + threadIdx.x;
  int r = recv[e];
  int pos = atomicAdd(&cursor[r], 1);
  eperm[pos] = e;
}

// one MFMA slice pass: 4 kk x (2 aF + 4 bF reads, 8 MFMAs)
__device__ __forceinline__ void cslice(const u16* __restrict__ bufA,
                                       const u16* __restrict__ bufB,
                                       f32x4 (&acc)[2][4],
                                       int wr, int wc, int fr, int fkq)
{
  #pragma unroll
  for (int kk = 0; kk < 4; ++kk) {
    bf16x8 aF[2], bF[4];
    #pragma unroll
    for (int m = 0; m < 2; ++m) {
      int row = wr * 32 + m * 16 + fr;
      int ch = (kk * 4 + fkq) ^ (row & 7);
      aF[m] = __builtin_bit_cast(bf16x8,
          *reinterpret_cast<const uint4*>(bufA + (row << 7) + (ch << 3)));
    }
    #pragma unroll
    for (int n = 0; n < 4; ++n) {
      int c = wc * 64 + n * 16 + fr;
      int ch = (kk * 4 + fkq) ^ (c & 7);
      bF[n] = __builtin_bit_cast(bf16x8,
          *reinterpret_cast<const uint4*>(bufB + (c << 7) + (ch << 3)));
    }
    __builtin_amdgcn_s_setprio(1);
    #pragma unroll
    for (int m = 0; m < 2; ++m)
      #pragma unroll
      for (int n = 0; n < 4; ++n)
        acc[m][n] = __builtin_amdgcn_mfma_f32_16x16x32_bf16(aF[m], bF[n], acc[m][n], 0, 0, 0);
    __builtin_amdgcn_s_setprio(0);
  }
}

// ------------------------------------------------------------ edge MLP ----
// 128 CSR-ordered edges/block, 8 waves (wave tile 32x64). Deep pipeline:
// all A0/B0/A1/B1 glds + eattr reg-loads issued up front; counted vmcnt +
// raw s_barrier (no full drains); B2/w2 glds slotted under compute.
// Fused scatter-mean: bf16 msg -> reused sB0, segmented column reduce,
// one atomicAdd per (segment,col) into sums.
__global__ __launch_bounds__(512, 2) void edge_mlp(
    const u16* __restrict__ xb, const float* __restrict__ eattr,
    const int* __restrict__ send, const int* __restrict__ recv,
    const int* __restrict__ eperm,
    const u16* __restrict__ w1Ts, const float* __restrict__ b1,
    const u16* __restrict__ w2Ts, const float* __restrict__ b2,
    float* __restrict__ msg_out, float* __restrict__ sums)
{
  __shared__ u16 sA0[128 * 128];
  __shared__ u16 sA1[128 * 128];
  __shared__ u16 sB0[128 * 128];
  __shared__ u16 sB1[128 * 128];

  const int tid  = threadIdx.x;
  const int lane = tid & 63;
  const int w    = tid >> 6;
  const int wr   = w >> 1;              // 0..3: 32-edge stripe
  const int wc   = w & 1;               // 0..1: 64-col half
  const int fr   = lane & 15;
  const int fkq  = lane >> 4;
  const int orow = fkq * 4;
  const int e0   = blockIdx.x * 128;
  const int lrow4 = lane >> 4;
  const int schk  = lane & 15;

  // --- prologue scalar-ish loads (drained before counting starts) ---
  int eo[4], ns[4], nr[4];
  #pragma unroll
  for (int i = 0; i < 4; ++i) eo[i] = eperm[e0 + w * 16 + i * 4 + lrow4];
  #pragma unroll
  for (int i = 0; i < 4; ++i) { ns[i] = send[eo[i]]; nr[i] = recv[eo[i]]; }
  float b1v[4], b2v[4];
  #pragma unroll
  for (int n = 0; n < 4; ++n) {
    b1v[n] = b1[wc * 64 + n * 16 + fr];
    b2v[n] = b2[wc * 64 + n * 16 + fr];
  }
  WV(0);                                // outstanding vmem = 0 from here

  // group 1: A0 (x[send]) -> sA0, B0 -> sB0   [8 glds]
  #pragma unroll
  for (int i = 0; i < 4; ++i) {
    int rloc = w * 16 + i * 4 + lrow4;
    gld16(xb + ((size_t)ns[i] << 7) + ((schk ^ (rloc & 7)) << 3),
          sA0 + ((w * 16 + i * 4) << 7));
  }
  #pragma unroll
  for (int i = 0; i < 4; ++i)
    gld16(w1Ts + ((w * 16 + i * 4) << 7) + (lane << 3),
          sB0 + ((w * 16 + i * 4) << 7));
  __builtin_amdgcn_sched_barrier(0);
  // group 2: A1 (x[recv]) -> sA1, B1 -> sB1   [8 glds]
  #pragma unroll
  for (int i = 0; i < 4; ++i) {
    int rloc = w * 16 + i * 4 + lrow4;
    gld16(xb + ((size_t)nr[i] << 7) + ((schk ^ (rloc & 7)) << 3),
          sA1 + ((w * 16 + i * 4) << 7));
  }
  #pragma unroll
  for (int i = 0; i < 4; ++i)
    gld16(w1Ts + 16384 + ((w * 16 + i * 4) << 7) + (lane << 3),
          sB1 + ((w * 16 + i * 4) << 7));
  __builtin_amdgcn_sched_barrier(0);
  // group 3: eattr -> regs                    [8 float4]
  float4 ea0[4], ea1[4];
  #pragma unroll
  for (int i = 0; i < 4; ++i) {
    int rloc = w * 16 + i * 4 + lrow4;
    const float* ep = eattr + ((size_t)eo[i] << 7) + ((schk ^ (rloc & 7)) << 3);
    ea0[i] = *reinterpret_cast<const float4*>(ep);
    ea1[i] = *reinterpret_cast<const float4*>(ep + 4);
  }
  __builtin_amdgcn_sched_barrier(0);

  f32x4 acc[2][4];
  #pragma unroll
  for (int m = 0; m < 2; ++m)
    #pragma unroll
    for (int n = 0; n < 4; ++n)
      #pragma unroll
      for (int r = 0; r < 4; ++r) acc[m][n][r] = 0.f;

  WV(16); bar();                        // A0,B0 landed (A1,B1,eattr in flight)
  cslice(sA0, sB0, acc, wr, wc, fr, fkq);              // c0: x[send] @ W1a
  WV(8); bar();                         // A1,B1 landed (eattr in flight)

  // B2 -> sB0 (freed by the barrier above)
  #pragma unroll
  for (int i = 0; i < 4; ++i)
    gld16(w1Ts + 32768 + ((w * 16 + i * 4) << 7) + (lane << 3),
          sB0 + ((w * 16 + i * 4) << 7));
  // slice-2 A: cvt eattr regs -> sA0 (compiler waits the eattr loads only)
  #pragma unroll
  for (int i = 0; i < 4; ++i) {
    int rloc = w * 16 + i * 4 + lrow4;
    *reinterpret_cast<uint4*>(sA0 + (rloc << 7) + (schk << 3)) =
        __builtin_bit_cast(uint4, cvt8(ea0[i], ea1[i]));
  }
  cslice(sA1, sB1, acc, wr, wc, fr, fkq);              // c1: x[recv] @ W1b
  WVL(0); bar();                        // B2 + slice-2 ds_writes complete

  // w2 -> sB1 (freed by the barrier above)
  #pragma unroll
  for (int i = 0; i < 4; ++i)
    gld16(w2Ts + ((w * 16 + i * 4) << 7) + (lane << 3),
          sB1 + ((w * 16 + i * 4) << 7));
  cslice(sA0, sB0, acc, wr, wc, fr, fkq);              // c2: eattr @ W1c

  // hidden = silu(acc + b1) -> sA1 (swizzled b16); reset acc
  #pragma unroll
  for (int n = 0; n < 4; ++n) {
    #pragma unroll
    for (int m = 0; m < 2; ++m)
      #pragma unroll
      for (int r = 0; r < 4; ++r) {
        int c = wc * 64 + n * 16 + fr;
        int row = wr * 32 + m * 16 + orow + r;
        sA1[(row << 7) + (((c >> 3) ^ (row & 7)) << 3) + (c & 7)] =
            f2bf(silu_f(acc[m][n][r] + b1v[n]));
        acc[m][n][r] = 0.f;
      }
  }
  WVL(0); bar();                        // w2 + hidden writes complete
  cslice(sA1, sB1, acc, wr, wc, fr, fkq);              // c3: hidden @ W2

  // snid -> sA0 head (sA0 free; c2 readers are past the pre-c3 barrier)
  int* snid = reinterpret_cast<int*>(sA0);
  #pragma unroll
  for (int i = 0; i < 4; ++i) snid[w * 16 + i * 4 + lrow4] = nr[i];

  // epilogue: msg = silu(acc + b2) -> global (by true edge id) + bf16 -> sB0
  #pragma unroll
  for (int m = 0; m < 2; ++m) {
    int eg[4];
    #pragma unroll
    for (int r = 0; r < 4; ++r)
      eg[r] = eperm[e0 + wr * 32 + m * 16 + orow + r];
    #pragma unroll
    for (int r = 0; r < 4; ++r) {
      int row = wr * 32 + m * 16 + orow + r;
      float* mp = msg_out + ((size_t)eg[r] << 7);
      #pragma unroll
      for (int n = 0; n < 4; ++n) {
        int c = wc * 64 + n * 16 + fr;
        float v = silu_f(acc[m][n][r] + b2v[n]);
        mp[c] = v;
        sB0[(row << 7) + (((c >> 3) ^ (row & 7)) << 3) + (c & 7)] = f2bf(v);
      }
    }
  }
  WL(); bar();                          // snid + msg-LDS visible to all

  // segmented column reduce: 4 threads/col x 32 rows each
  {
    const int col = tid & 127, q = tid >> 7;
    const int row0 = q * 32;
    float s = 0.f;
    int cur = snid[row0];
    #pragma unroll 1
    for (int r = 0; r < 32; ++r) {
      int row = row0 + r;
      u16 hv = sB0[(row << 7) + (((col >> 3) ^ (row & 7)) << 3) + (col & 7)];
      s += __builtin_bit_cast(float, (u32)hv << 16);
      int nxt = (r < 31) ? snid[row + 1] : -1;
      if (nxt != cur) {
        atomicAdd(sums + (size_t)cur * HID + col, s);
        s = 0.f;
        cur = nxt;
      }
    }
  }
}

// ----------------------------------------------------------- node side ----
// xob = bf16(x + sums/max(cnt,1))
__global__ __launch_bounds__(256) void xin_k(
    const float* __restrict__ x, const float* __restrict__ sums,
    const int* __restrict__ cnt, u16* __restrict__ xob)
{
  int idx = blockIdx.x * 256 + threadIdx.x;   // NN*HID/4 float4s
  int node = idx >> 5;
  float inv = 1.f / fmaxf((float)cnt[node], 1.f);
  float4 xv = reinterpret_cast<const float4*>(x)[idx];
  float4 sv = reinterpret_cast<const float4*>(sums)[idx];
  float o0 = xv.x + sv.x * inv, o1 = xv.y + sv.y * inv;
  float o2 = xv.z + sv.z * inv, o3 = xv.w + sv.w * inv;
  uint2 wv;
  wv.x = (u32)f2bf(o0) | ((u32)f2bf(o1) << 16);
  wv.y = (u32)f2bf(o2) | ((u32)f2bf(o3) << 16);
  reinterpret_cast<uint2*>(xob)[idx] = wv;
}

// t = silu(xo_in @ wu1 + bu1)  [NN,256]  (R3 LDS-staged version)
__global__ __launch_bounds__(256) void mlp1_k(
    const u16* __restrict__ xob, const u16* __restrict__ wu1T,
    const float* __restrict__ bu1, u16* __restrict__ t)
{
  __shared__ u16 sB[256][40];
  const int tid = threadIdx.x, lane = tid & 63, wid = tid >> 6;
  const int wr = wid >> 1, wc = wid & 1;
  const int fr = lane & 15, fk = (lane >> 4) * 8, orow = (lane >> 4) * 4;
  const int n0 = blockIdx.x * 64;

  f32x4 acc[2][8];
  #pragma unroll
  for (int m = 0; m < 2; ++m)
    #pragma unroll
    for (int n = 0; n < 8; ++n)
      #pragma unroll
      for (int r = 0; r < 4; ++r) acc[m][n][r] = 0.f;

  #pragma unroll 1
  for (int kk = 0; kk < 4; ++kk) {
    #pragma unroll
    for (int it = 0; it < 4; ++it) {
      int chunk = tid + it * 256;
      int c = chunk >> 2, q = chunk & 3;
      *reinterpret_cast<uint4*>(&sB[c][q * 8]) =
          *reinterpret_cast<const uint4*>(wu1T + c * 128 + kk * 32 + q * 8);
    }
    __syncthreads();
    bf16x8 aF[2], bF[8];
    #pragma unroll
    for (int m = 0; m < 2; ++m)
      aF[m] = __builtin_bit_cast(bf16x8, *reinterpret_cast<const uint4*>(
          xob + (size_t)(n0 + wr * 32 + m * 16 + fr) * HID + kk * 32 + fk));
    #pragma unroll
    for (int n = 0; n < 8; ++n)
      bF[n] = __builtin_bit_cast(bf16x8,
          *reinterpret_cast<const uint4*>(&sB[wc * 128 + n * 16 + fr][fk]));
    #pragma unroll
    for (int m = 0; m < 2; ++m)
      #pragma unroll
      for (int n = 0; n < 8; ++n)
        acc[m][n] = __builtin_amdgcn_mfma_f32_16x16x32_bf16(aF[m], bF[n], acc[m][n], 0, 0, 0);
    __syncthreads();
  }
  #pragma unroll
  for (int n = 0; n < 8; ++n) {
    int col = wc * 128 + n * 16 + fr;
    float bb = bu1[col];
    #pragma unroll
    for (int m = 0; m < 2; ++m) {
      int row = n0 + wr * 32 + m * 16 + orow;
      #pragma unroll
      for (int r = 0; r < 4; ++r)
        t[(size_t)(row + r) * 256 + col] = f2bf(silu_f(acc[m][n][r] + bb));
    }
  }
}

// xo = (x + sums/cnt) + t @ wu2 + bu2   (residual recomputed in f32)
__global__ __launch_bounds__(256) void mlp2_k(
    const u16* __restrict__ t, const u16* __restrict__ wu2T,
    const float* __restrict__ bu2, const float* __restrict__ x,
    const float* __restrict__ sums, const int* __restrict__ cnt,
    float* __restrict__ xo)
{
  __shared__ u16 sB[128][40];
  const int tid = threadIdx.x, lane = tid & 63, wid = tid >> 6;
  const int wr = wid >> 1, wc = wid & 1;
  const int fr = lane & 15, fk = (lane >> 4) * 8, orow = (lane >> 4) * 4;
  const int n0 = blockIdx.x * 64;

  f32x4 acc[2][4];
  #pragma unroll
  for (int m = 0; m < 2; ++m)
    #pragma unroll
    for (int n = 0; n < 4; ++n)
      #pragma unroll
      for (int r = 0; r < 4; ++r) acc[m][n][r] = 0.f;

  #pragma unroll 1
  for (int kk = 0; kk < 8; ++kk) {
    #pragma unroll
    for (int it = 0; it < 2; ++it) {
      int chunk = tid + it * 256;
      int c = chunk >> 2, q = chunk & 3;
      *reinterpret_cast<uint4*>(&sB[c][q * 8]) =
          *reinterpret_cast<const uint4*>(wu2T + c * 256 + kk * 32 + q * 8);
    }
    __syncthreads();
    bf16x8 aF[2], bF[4];
    #pragma unroll
    for (int m = 0; m < 2; ++m)
      aF[m] = __builtin_bit_cast(bf16x8, *reinterpret_cast<const uint4*>(
          t + (size_t)(n0 + wr * 32 + m * 16 + fr) * 256 + kk * 32 + fk));
    #pragma unroll
    for (int n = 0; n < 4; ++n)
      bF[n] = __builtin_bit_cast(bf16x8,
          *reinterpret_cast<const uint4*>(&sB[wc * 64 + n * 16 + fr][fk]));
    #pragma unroll
    for (int m = 0; m < 2; ++m)
      #pragma unroll
      for (int n = 0; n < 4; ++n)
        acc[m][n] = __builtin_amdgcn_mfma_f32_16x16x32_bf16(aF[m], bF[n], acc[m][n], 0, 0, 0);
    __syncthreads();
  }
  #pragma unroll
  for (int m = 0; m < 2; ++m) {
    #pragma unroll
    for (int r = 0; r < 4; ++r) {
      int gn = n0 + wr * 32 + m * 16 + orow + r;
      float inv = 1.f / fmaxf((float)cnt[gn], 1.f);
      #pragma unroll
      for (int n = 0; n < 4; ++n) {
        int col = wc * 64 + n * 16 + fr;
        float xi = x[(size_t)gn * HID + col] + sums[(size_t)gn * HID + col] * inv;
        xo[(size_t)gn * HID + col] = xi + acc[m][n][r] + bu2[col];
      }
    }
  }
}

// -------------------------------------------------------------- launch ----
extern "C" void kernel_launch(void* const* d_in, const int* in_sizes, int n_in,
                              void* d_out, int out_size, void* d_ws, size_t ws_size,
                              hipStream_t stream)
{
  (void)in_sizes; (void)n_in; (void)out_size; (void)ws_size;
  const float* x     = (const float*)d_in[0];
  const float* eattr = (const float*)d_in[1];
  const int*   edges = (const int*)d_in[2];
  const float* w1  = (const float*)d_in[3];
  const float* b1  = (const float*)d_in[4];
  const float* w2  = (const float*)d_in[5];
  const float* b2  = (const float*)d_in[6];
  const float* wu1 = (const float*)d_in[7];
  const float* bu1 = (const float*)d_in[8];
  const float* wu2 = (const float*)d_in[9];
  const float* bu2 = (const float*)d_in[10];

  float* xo  = (float*)d_out;
  float* msg = xo + (size_t)NN * HID;

  char* p = (char*)d_ws;                       // ~53 MB total
  u16* xb    = (u16*)p; p += (size_t)NN * HID * 2;
  u16* w1Ts  = (u16*)p; p += 384 * 128 * 2;
  u16* w2Ts  = (u16*)p; p += 128 * 128 * 2;
  u16* wu1T  = (u16*)p; p += 256 * 128 * 2;
  u16* wu2T  = (u16*)p; p += 128 * 256 * 2;
  u16* xob   = (u16*)p; p += (size_t)NN * HID * 2;
  u16* tbuf  = (u16*)p; p += (size_t)NN * 256 * 2;
  float* sums = (float*)p; p += (size_t)NN * HID * 4;
  int* cnt    = (int*)p; p += (size_t)NN * 4;
  int* off    = (int*)p; p += (size_t)(NN + 64) * 4;
  int* cursor = (int*)p; p += (size_t)NN * 4;
  int* eperm  = (int*)p; p += (size_t)NE * 4;

  const int* send = edges;
  const int* recv = edges + NE;

  hipMemsetAsync(cnt, 0, (size_t)NN * 4, stream);
  hipMemsetAsync(sums, 0, (size_t)NN * HID * 4, stream);
  prep_k<<<NN * HID / 256, 256, 0, stream>>>(x, w1, w2, wu1, wu2, recv,
                                             xb, w1Ts, w2Ts, wu1T, wu2T, cnt);
  scan_k<<<1, 1024, 0, stream>>>(cnt, off, cursor);
  scatter_k<<<NE / 256, 256, 0, stream>>>(recv, cursor, eperm);
  edge_mlp<<<NE / 128, 512, 0, stream>>>(xb, eattr, send, recv, eperm,
                                         w1Ts, b1, w2Ts, b2, msg, sums);
  xin_k<<<NN * HID / 4 / 256, 256, 0, stream>>>(x, sums, cnt, xob);
  mlp1_k<<<NN / 64, 256, 0, stream>>>(xob, wu1T, bu1, tbuf);
  mlp2_k<<<NN / 64, 256, 0, stream>>>(tbuf, wu2T, bu2, x, sums, cnt, xo);
}

// Round 6
// 336.117 us; speedup vs baseline: 1.6253x; 1.1631x over previous
//
#include <hip/hip_runtime.h>
#include <hip/hip_bf16.h>

#define NN 32768
#define NE 524288
#define HID 128

typedef unsigned short u16;
typedef unsigned int u32;
typedef __bf16 bf16x8 __attribute__((ext_vector_type(8)));
typedef float f32x4 __attribute__((ext_vector_type(4)));

__device__ __forceinline__ u16 f2bf(float f) {
  return __builtin_bit_cast(u16, (__bf16)f);   // RNE via v_cvt
}
__device__ __forceinline__ float silu_f(float v) {
  return v * __builtin_amdgcn_rcpf(1.f + __expf(-v));
}
__device__ __forceinline__ uint4 cvt8u(float4 a, float4 b) {
  bf16x8 r;
  r[0] = (__bf16)a.x; r[1] = (__bf16)a.y; r[2] = (__bf16)a.z; r[3] = (__bf16)a.w;
  r[4] = (__bf16)b.x; r[5] = (__bf16)b.y; r[6] = (__bf16)b.z; r[7] = (__bf16)b.w;
  return __builtin_bit_cast(uint4, r);
}

// async global->LDS, 16B/lane; LDS dest = wave-uniform base + lane*16
__device__ __forceinline__ void gld16(const void* g, void* l) {
  __builtin_amdgcn_global_load_lds(
      (const __attribute__((address_space(1))) u32*)g,
      (__attribute__((address_space(3))) u32*)l, 16, 0, 0);
}

#define WV(N)  do { asm volatile("s_waitcnt vmcnt(" #N ")" ::: "memory"); \
                    __builtin_amdgcn_sched_barrier(0); } while (0)
#define WVL(N) do { asm volatile("s_waitcnt vmcnt(" #N ") lgkmcnt(0)" ::: "memory"); \
                    __builtin_amdgcn_sched_barrier(0); } while (0)
#define WL()   do { asm volatile("s_waitcnt lgkmcnt(0)" ::: "memory"); \
                    __builtin_amdgcn_sched_barrier(0); } while (0)
__device__ __forceinline__ void bar() {
  __builtin_amdgcn_sched_barrier(0);
  __builtin_amdgcn_s_barrier();
  __builtin_amdgcn_sched_barrier(0);
}

// ---------------------------------------------------------------- prep ----
// x->bf16; w1/w2 -> col-major + 16B-chunk XOR pre-swizzle; wu1/wu2 plain
// col-major; fused recv-degree count (cnt pre-zeroed).
__global__ __launch_bounds__(256) void prep_k(
    const float* __restrict__ x, const float* __restrict__ w1,
    const float* __restrict__ w2, const float* __restrict__ wu1,
    const float* __restrict__ wu2, const int* __restrict__ recv,
    u16* __restrict__ xb, u16* __restrict__ w1Ts, u16* __restrict__ w2Ts,
    u16* __restrict__ wu1T, u16* __restrict__ wu2T, int* __restrict__ cnt)
{
  int i = blockIdx.x * 256 + threadIdx.x;   // grid covers exactly NN*HID
  xb[i] = f2bf(x[i]);
  if (i < NE) atomicAdd(&cnt[recv[i]], 1);
  if (i < 3 * 128 * 128) {                  // w1Ts [s][c][q^(c&7)][j]
    int j = i & 7, qs = (i >> 3) & 15, c = (i >> 7) & 127, s = i >> 14;
    int k = s * 128 + ((qs ^ (c & 7)) << 3) + j;
    w1Ts[i] = f2bf(w1[k * 128 + c]);
  }
  if (i < 128 * 128) {                      // w2Ts [c][q^(c&7)][j]
    int j = i & 7, qs = (i >> 3) & 15, c = i >> 7;
    int k = ((qs ^ (c & 7)) << 3) + j;
    w2Ts[i] = f2bf(w2[k * 128 + c]);
  }
  if (i < 256 * 128) { int c = i >> 7, k = i & 127; wu1T[i] = f2bf(wu1[k * 256 + c]); }
  if (i < 128 * 256) { int c = i >> 8, k = i & 255; wu2T[i] = f2bf(wu2[k * 128 + c]); }
}

// exclusive scan of cnt[NN] -> off[NN+1]; cursor = copy of off
__global__ __launch_bounds__(1024) void scan_k(const int* __restrict__ cnt,
                                               int* __restrict__ off,
                                               int* __restrict__ cursor)
{
  __shared__ int part[1024];
  const int tid = threadIdx.x;
  const int base = tid * 32;
  int v[32];
  int s = 0;
  #pragma unroll
  for (int j = 0; j < 32; ++j) { v[j] = cnt[base + j]; s += v[j]; }
  part[tid] = s;
  __syncthreads();
  #pragma unroll 1
  for (int d = 1; d < 1024; d <<= 1) {
    int t = (tid >= d) ? part[tid - d] : 0;
    __syncthreads();
    part[tid] += t;
    __syncthreads();
  }
  int ex = part[tid] - s;
  #pragma unroll
  for (int j = 0; j < 32; ++j) {
    off[base + j] = ex;
    cursor[base + j] = ex;
    ex += v[j];
  }
  if (tid == 1023) off[NN] = ex;
}

__global__ __launch_bounds__(256) void scatter_k(const int* __restrict__ recv,
                                                 int* __restrict__ cursor,
                                                 int* __restrict__ eperm)
{
  int e = blockIdx.x * 256 + threadIdx.x;
  int r = recv[e];
  int pos = atomicAdd(&cursor[r], 1);
  eperm[pos] = e;
}

// ------------------------------------------------------------ edge MLP ----
// 128 CSR-ordered edges/block as TWO 64-edge subtiles; 8 waves, wave tile
// 32x32 (wr=w>>2, wc=w&3). LDS 64.5KB -> 2 blocks/CU. Slice-outer pipeline:
// one 32KB B panel at a time; A subtiles double-buffered (sA0/sA1 16KB) with
// 1-phase-lookahead staging (WV always waits the stage issued one compute
// phase earlier). eattr slice reg-staged, loads issued one phase ahead.
// Fused scatter-mean epilogue (segmented column reduce + atomicAdd).
__global__ __launch_bounds__(512, 4) void edge_mlp(
    const u16* __restrict__ xb, const float* __restrict__ eattr,
    const int* __restrict__ send, const int* __restrict__ recv,
    const int* __restrict__ eperm,
    const u16* __restrict__ w1Ts, const float* __restrict__ b1,
    const u16* __restrict__ w2Ts, const float* __restrict__ b2,
    float* __restrict__ msg_out, float* __restrict__ sums)
{
  __shared__ u16 sA0[64 * 128];
  __shared__ u16 sA1[64 * 128];
  __shared__ u16 sB[128 * 128];
  __shared__ int sNid[128];

  const int tid  = threadIdx.x;
  const int lane = tid & 63;
  const int w    = tid >> 6;
  const int wr   = (w >> 2) & 1;        // 32-row stripe within 64-edge subtile
  const int wc   = w & 3;               // 32-col quarter
  const int fr   = lane & 15;
  const int fkq  = lane >> 4;
  const int orow = fkq * 4;
  const int e0   = blockIdx.x * 128;
  const int lrow4 = lane >> 4;
  const int schk  = lane & 15;

  // ---- staged-load helpers (lambdas keep indices compile-time) ----
  auto stageB = [&](const u16* src) {
    #pragma unroll
    for (int i = 0; i < 4; ++i)
      gld16(src + ((w * 16 + i * 4) << 7) + (lane << 3),
            sB + ((w * 16 + i * 4) << 7));
  };
  auto stageA = [&](u16* dst, int nA, int nB) {
    gld16(xb + ((size_t)nA << 7) + ((schk ^ lrow4) << 3),
          dst + ((w * 8) << 7));
    gld16(xb + ((size_t)nB << 7) + ((schk ^ (4 + lrow4)) << 3),
          dst + ((w * 8 + 4) << 7));
  };
  auto eaLoad = [&](int eoA, int eoB, float4 (&v)[4]) {
    const float* pA = eattr + ((size_t)eoA << 7) + ((schk ^ lrow4) << 3);
    const float* pB = eattr + ((size_t)eoB << 7) + ((schk ^ (4 + lrow4)) << 3);
    v[0] = *reinterpret_cast<const float4*>(pA);
    v[1] = *reinterpret_cast<const float4*>(pA + 4);
    v[2] = *reinterpret_cast<const float4*>(pB);
    v[3] = *reinterpret_cast<const float4*>(pB + 4);
  };
  auto eaWrite = [&](u16* dst, const float4 (&v)[4]) {
    *reinterpret_cast<uint4*>(dst + ((w * 8 + lrow4) << 7) + (schk << 3)) =
        cvt8u(v[0], v[1]);
    *reinterpret_cast<uint4*>(dst + ((w * 8 + 4 + lrow4) << 7) + (schk << 3)) =
        cvt8u(v[2], v[3]);
  };

  // ---- prologue ----
  stageB(w1Ts);                                        // B0 [4]
  int eoA[2], eoB[2], ns[2][2], nr[2][2];
  #pragma unroll
  for (int t = 0; t < 2; ++t) {
    eoA[t] = eperm[e0 + t * 64 + w * 8 + lrow4];
    eoB[t] = eperm[e0 + t * 64 + w * 8 + 4 + lrow4];
    ns[t][0] = send[eoA[t]]; ns[t][1] = send[eoB[t]];
    nr[t][0] = recv[eoA[t]]; nr[t][1] = recv[eoB[t]];
    sNid[t * 64 + w * 8 + lrow4] = nr[t][0];
    sNid[t * 64 + w * 8 + 4 + lrow4] = nr[t][1];
  }
  float b1v[2], b2v[2];
  #pragma unroll
  for (int n = 0; n < 2; ++n) {
    b1v[n] = b1[wc * 32 + n * 16 + fr];
    b2v[n] = b2[wc * 32 + n * 16 + fr];
  }

  f32x4 acc[2][2][2];
  #pragma unroll
  for (int t = 0; t < 2; ++t)
    #pragma unroll
    for (int m = 0; m < 2; ++m)
      #pragma unroll
      for (int n = 0; n < 2; ++n)
        #pragma unroll
        for (int r = 0; r < 4; ++r) acc[t][m][n][r] = 0.f;

  stageA(sA0, ns[0][0], ns[0][1]);                     // A(s0,t0) [2]
  stageA(sA1, ns[1][0], ns[1][1]);                     // A(s0,t1) [2]

  // one 32x32 slice pass vs current sB panel
  auto cs32 = [&](const u16* bufA, f32x4 (&a)[2][2]) {
    #pragma unroll
    for (int kk = 0; kk < 4; ++kk) {
      bf16x8 aF[2], bF[2];
      #pragma unroll
      for (int m = 0; m < 2; ++m) {
        int row = wr * 32 + m * 16 + fr;
        int ch = (kk * 4 + fkq) ^ (row & 7);
        aF[m] = __builtin_bit_cast(bf16x8,
            *reinterpret_cast<const uint4*>(bufA + (row << 7) + (ch << 3)));
      }
      #pragma unroll
      for (int n = 0; n < 2; ++n) {
        int c = wc * 32 + n * 16 + fr;
        int ch = (kk * 4 + fkq) ^ (c & 7);
        bF[n] = __builtin_bit_cast(bf16x8,
            *reinterpret_cast<const uint4*>(sB + (c << 7) + (ch << 3)));
      }
      __builtin_amdgcn_s_setprio(1);
      #pragma unroll
      for (int m = 0; m < 2; ++m)
        #pragma unroll
        for (int n = 0; n < 2; ++n)
          a[m][n] = __builtin_amdgcn_mfma_f32_16x16x32_bf16(aF[m], bF[n], a[m][n], 0, 0, 0);
      __builtin_amdgcn_s_setprio(0);
    }
  };

  WV(2); bar();                          // B0 + A(s0,t0) landed; A(s0,t1) rides
  // ---- slice 0: x[send] @ W1a ----
  cs32(sA0, acc[0]); bar();
  stageA(sA0, nr[0][0], nr[0][1]);       // A(s1,t0)
  WV(2); bar();                          // A(s0,t1) landed
  cs32(sA1, acc[1]); bar();
  stageB(w1Ts + 16384);                  // B1
  stageA(sA1, nr[1][0], nr[1][1]);       // A(s1,t1)
  WV(2); bar();                          // A(s1,t0)+B1 landed; A(s1,t1) rides
  // ---- slice 1: x[recv] @ W1b ----
  cs32(sA0, acc[0]); bar();
  float4 ea0[4], ea1[4];
  eaLoad(eoA[0], eoB[0], ea0);           // eattr t0 (rides)
  WV(4); bar();                          // A(s1,t1) landed; ea0 rides
  cs32(sA1, acc[1]); bar();
  stageB(w1Ts + 32768);                  // B2
  eaLoad(eoA[1], eoB[1], ea1);           // eattr t1 (rides)
  eaWrite(sA0, ea0);                     // compiler waits ea0 only
  WV(4);                                 // B2 landed; ea1 rides
  WL(); bar();
  // ---- slice 2: eattr @ W1c ----
  cs32(sA0, acc[0]); bar();
  eaWrite(sA1, ea1);
  WL(); bar();
  cs32(sA1, acc[1]); bar();

  // ---- layer 2: hidden @ W2 ----
  stageB(w2Ts);                          // w2
  #pragma unroll
  for (int t = 0; t < 2; ++t) {          // hidden = silu(acc+b1) -> sA[t]
    u16* dst = t ? sA1 : sA0;
    #pragma unroll
    for (int m = 0; m < 2; ++m)
      #pragma unroll
      for (int n = 0; n < 2; ++n) {
        int c = wc * 32 + n * 16 + fr;
        #pragma unroll
        for (int r = 0; r < 4; ++r) {
          int row = wr * 32 + m * 16 + orow + r;
          dst[(row << 7) + (((c >> 3) ^ (row & 7)) << 3) + (c & 7)] =
              f2bf(silu_f(acc[t][m][n][r] + b1v[n]));
          acc[t][m][n][r] = 0.f;
        }
      }
  }
  WVL(0); bar();
  cs32(sA0, acc[0]); bar();
  cs32(sA1, acc[1]);

  // ---- epilogue: msg out (global, true edge ids) ----
  #pragma unroll
  for (int t = 0; t < 2; ++t) {
    #pragma unroll
    for (int m = 0; m < 2; ++m) {
      #pragma unroll
      for (int r = 0; r < 4; ++r) {
        int eg = eperm[e0 + t * 64 + wr * 32 + m * 16 + orow + r];
        float* mp = msg_out + ((size_t)eg << 7);
        #pragma unroll
        for (int n = 0; n < 2; ++n)
          mp[wc * 32 + n * 16 + fr] = silu_f(acc[t][m][n][r] + b2v[n]);
      }
    }
  }
  bar();                                 // sA0/sA1 free
  // bf16 msg -> sA0/sA1 for the reduce
  #pragma unroll
  for (int t = 0; t < 2; ++t) {
    u16* dst = t ? sA1 : sA0;
    #pragma unroll
    for (int m = 0; m < 2; ++m)
      #pragma unroll
      for (int n = 0; n < 2; ++n) {
        int c = wc * 32 + n * 16 + fr;
        #pragma unroll
        for (int r = 0; r < 4; ++r) {
          int row = wr * 32 + m * 16 + orow + r;
          dst[(row << 7) + (((c >> 3) ^ (row & 7)) << 3) + (c & 7)] =
              f2bf(silu_f(acc[t][m][n][r] + b2v[n]));
        }
      }
  }
  WL(); bar();
  // segmented column reduce: 4 thread-groups x 32 rows, 128 cols
  {
    const int col = tid & 127, q = tid >> 7;
    const u16* bp = (q < 2) ? sA0 : sA1;
    float s = 0.f;
    int cur = sNid[q * 32];
    #pragma unroll 1
    for (int r = 0; r < 32; ++r) {
      int g = q * 32 + r;
      int lrow = g & 63;
      u16 hv = bp[(lrow << 7) + (((col >> 3) ^ (lrow & 7)) << 3) + (col & 7)];
      s += __builtin_bit_cast(float, (u32)hv << 16);
      int nxt = (r < 31) ? sNid[g + 1] : -1;
      if (nxt != cur) {
        atomicAdd(sums + (size_t)cur * HID + col, s);
        s = 0.f;
        cur = nxt;
      }
    }
  }
}

// ----------------------------------------------------------- node side ----
// xob = bf16(x + sums/max(cnt,1))
__global__ __launch_bounds__(256) void xin_k(
    const float* __restrict__ x, const float* __restrict__ sums,
    const int* __restrict__ cnt, u16* __restrict__ xob)
{
  int idx = blockIdx.x * 256 + threadIdx.x;   // NN*HID/4 float4s
  int node = idx >> 5;
  float inv = 1.f / fmaxf((float)cnt[node], 1.f);
  float4 xv = reinterpret_cast<const float4*>(x)[idx];
  float4 sv = reinterpret_cast<const float4*>(sums)[idx];
  float o0 = xv.x + sv.x * inv, o1 = xv.y + sv.y * inv;
  float o2 = xv.z + sv.z * inv, o3 = xv.w + sv.w * inv;
  uint2 wv;
  wv.x = (u32)f2bf(o0) | ((u32)f2bf(o1) << 16);
  wv.y = (u32)f2bf(o2) | ((u32)f2bf(o3) << 16);
  reinterpret_cast<uint2*>(xob)[idx] = wv;
}

// t = silu(xo_in @ wu1 + bu1)  [NN,256]
__global__ __launch_bounds__(256) void mlp1_k(
    const u16* __restrict__ xob, const u16* __restrict__ wu1T,
    const float* __restrict__ bu1, u16* __restrict__ t)
{
  __shared__ u16 sB[256][40];
  const int tid = threadIdx.x, lane = tid & 63, wid = tid >> 6;
  const int wr = wid >> 1, wc = wid & 1;
  const int fr = lane & 15, fk = (lane >> 4) * 8, orow = (lane >> 4) * 4;
  const int n0 = blockIdx.x * 64;

  f32x4 acc[2][8];
  #pragma unroll
  for (int m = 0; m < 2; ++m)
    #pragma unroll
    for (int n = 0; n < 8; ++n)
      #pragma unroll
      for (int r = 0; r < 4; ++r) acc[m][n][r] = 0.f;

  #pragma unroll 1
  for (int kk = 0; kk < 4; ++kk) {
    #pragma unroll
    for (int it = 0; it < 4; ++it) {
      int chunk = tid + it * 256;
      int c = chunk >> 2, q = chunk & 3;
      *reinterpret_cast<uint4*>(&sB[c][q * 8]) =
          *reinterpret_cast<const uint4*>(wu1T + c * 128 + kk * 32 + q * 8);
    }
    __syncthreads();
    bf16x8 aF[2], bF[8];
    #pragma unroll
    for (int m = 0; m < 2; ++m)
      aF[m] = __builtin_bit_cast(bf16x8, *reinterpret_cast<const uint4*>(
          xob + (size_t)(n0 + wr * 32 + m * 16 + fr) * HID + kk * 32 + fk));
    #pragma unroll
    for (int n = 0; n < 8; ++n)
      bF[n] = __builtin_bit_cast(bf16x8,
          *reinterpret_cast<const uint4*>(&sB[wc * 128 + n * 16 + fr][fk]));
    #pragma unroll
    for (int m = 0; m < 2; ++m)
      #pragma unroll
      for (int n = 0; n < 8; ++n)
        acc[m][n] = __builtin_amdgcn_mfma_f32_16x16x32_bf16(aF[m], bF[n], acc[m][n], 0, 0, 0);
    __syncthreads();
  }
  #pragma unroll
  for (int n = 0; n < 8; ++n) {
    int col = wc * 128 + n * 16 + fr;
    float bb = bu1[col];
    #pragma unroll
    for (int m = 0; m < 2; ++m) {
      int row = n0 + wr * 32 + m * 16 + orow;
      #pragma unroll
      for (int r = 0; r < 4; ++r)
        t[(size_t)(row + r) * 256 + col] = f2bf(silu_f(acc[m][n][r] + bb));
    }
  }
}

// xo = (x + sums/cnt) + t @ wu2 + bu2   (residual recomputed in f32)
__global__ __launch_bounds__(256) void mlp2_k(
    const u16* __restrict__ t, const u16* __restrict__ wu2T,
    const float* __restrict__ bu2, const float* __restrict__ x,
    const float* __restrict__ sums, const int* __restrict__ cnt,
    float* __restrict__ xo)
{
  __shared__ u16 sB[128][40];
  const int tid = threadIdx.x, lane = tid & 63, wid = tid >> 6;
  const int wr = wid >> 1, wc = wid & 1;
  const int fr = lane & 15, fk = (lane >> 4) * 8, orow = (lane >> 4) * 4;
  const int n0 = blockIdx.x * 64;

  f32x4 acc[2][4];
  #pragma unroll
  for (int m = 0; m < 2; ++m)
    #pragma unroll
    for (int n = 0; n < 4; ++n)
      #pragma unroll
      for (int r = 0; r < 4; ++r) acc[m][n][r] = 0.f;

  #pragma unroll 1
  for (int kk = 0; kk < 8; ++kk) {
    #pragma unroll
    for (int it = 0; it < 2; ++it) {
      int chunk = tid + it * 256;
      int c = chunk >> 2, q = chunk & 3;
      *reinterpret_cast<uint4*>(&sB[c][q * 8]) =
          *reinterpret_cast<const uint4*>(wu2T + c * 256 + kk * 32 + q * 8);
    }
    __syncthreads();
    bf16x8 aF[2], bF[4];
    #pragma unroll
    for (int m = 0; m < 2; ++m)
      aF[m] = __builtin_bit_cast(bf16x8, *reinterpret_cast<const uint4*>(
          t + (size_t)(n0 + wr * 32 + m * 16 + fr) * 256 + kk * 32 + fk));
    #pragma unroll
    for (int n = 0; n < 4; ++n)
      bF[n] = __builtin_bit_cast(bf16x8,
          *reinterpret_cast<const uint4*>(&sB[wc * 64 + n * 16 + fr][fk]));
    #pragma unroll
    for (int m = 0; m < 2; ++m)
      #pragma unroll
      for (int n = 0; n < 4; ++n)
        acc[m][n] = __builtin_amdgcn_mfma_f32_16x16x32_bf16(aF[m], bF[n], acc[m][n], 0, 0, 0);
    __syncthreads();
  }
  #pragma unroll
  for (int m = 0; m < 2; ++m) {
    #pragma unroll
    for (int r = 0; r < 4; ++r) {
      int gn = n0 + wr * 32 + m * 16 + orow + r;
      float inv = 1.f / fmaxf((float)cnt[gn], 1.f);
      #pragma unroll
      for (int n = 0; n < 4; ++n) {
        int col = wc * 64 + n * 16 + fr;
        float xi = x[(size_t)gn * HID + col] + sums[(size_t)gn * HID + col] * inv;
        xo[(size_t)gn * HID + col] = xi + acc[m][n][r] + bu2[col];
      }
    }
  }
}

// -------------------------------------------------------------- launch ----
extern "C" void kernel_launch(void* const* d_in, const int* in_sizes, int n_in,
                              void* d_out, int out_size, void* d_ws, size_t ws_size,
                              hipStream_t stream)
{
  (void)in_sizes; (void)n_in; (void)out_size; (void)ws_size;
  const float* x     = (const float*)d_in[0];
  const float* eattr = (const float*)d_in[1];
  const int*   edges = (const int*)d_in[2];
  const float* w1  = (const float*)d_in[3];
  const float* b1  = (const float*)d_in[4];
  const float* w2  = (const float*)d_in[5];
  const float* b2  = (const float*)d_in[6];
  const float* wu1 = (const float*)d_in[7];
  const float* bu1 = (const float*)d_in[8];
  const float* wu2 = (const float*)d_in[9];
  const float* bu2 = (const float*)d_in[10];

  float* xo  = (float*)d_out;
  float* msg = xo + (size_t)NN * HID;

  char* p = (char*)d_ws;                       // ~53 MB total
  u16* xb    = (u16*)p; p += (size_t)NN * HID * 2;
  u16* w1Ts  = (u16*)p; p += 384 * 128 * 2;
  u16* w2Ts  = (u16*)p; p += 128 * 128 * 2;
  u16* wu1T  = (u16*)p; p += 256 * 128 * 2;
  u16* wu2T  = (u16*)p; p += 128 * 256 * 2;
  u16* xob   = (u16*)p; p += (size_t)NN * HID * 2;
  u16* tbuf  = (u16*)p; p += (size_t)NN * 256 * 2;
  float* sums = (float*)p; p += (size_t)NN * HID * 4;
  int* cnt    = (int*)p; p += (size_t)NN * 4;
  int* off    = (int*)p; p += (size_t)(NN + 64) * 4;
  int* cursor = (int*)p; p += (size_t)NN * 4;
  int* eperm  = (int*)p; p += (size_t)NE * 4;

  const int* send = edges;
  const int* recv = edges + NE;

  hipMemsetAsync(cnt, 0, (size_t)NN * 4, stream);
  hipMemsetAsync(sums, 0, (size_t)NN * HID * 4, stream);
  prep_k<<<NN * HID / 256, 256, 0, stream>>>(x, w1, w2, wu1, wu2, recv,
                                             xb, w1Ts, w2Ts, wu1T, wu2T, cnt);
  scan_k<<<1, 1024, 0, stream>>>(cnt, off, cursor);
  scatter_k<<<NE / 256, 256, 0, stream>>>(recv, cursor, eperm);
  edge_mlp<<<NE / 128, 512, 0, stream>>>(xb, eattr, send, recv, eperm,
                                         w1Ts, b1, w2Ts, b2, msg, sums);
  xin_k<<<NN * HID / 4 / 256, 256, 0, stream>>>(x, sums, cnt, xob);
  mlp1_k<<<NN / 64, 256, 0, stream>>>(xob, wu1T, bu1, tbuf);
  mlp2_k<<<NN / 64, 256, 0, stream>>>(tbuf, wu2T, bu2, x, sums, cnt, xo);
}